// Round 5
// baseline (303.246 us; speedup 1.0000x reference)
//
#include <hip/hip_runtime.h>
#include <hip/hip_fp16.h>

#define NN 50000
#define D 128
#define SCAN_BS 512

typedef __attribute__((ext_vector_type(8))) short bf16x8;
typedef __attribute__((ext_vector_type(16))) float f32x16;
typedef _Float16 h16;
typedef __attribute__((ext_vector_type(4))) _Float16 h16x4;
typedef __attribute__((ext_vector_type(8))) _Float16 h16x8;

static __device__ __forceinline__ short bf16_rne(float f) {
    unsigned u = __float_as_uint(f);
    unsigned r = (u + 0x7FFFu + ((u >> 16) & 1u)) >> 16;
    return (short)r;
}

// ---------------- preprocessing ----------------

// fused: zero cnt[] + pack 3 weight matrices into MFMA fragment layout
// Wf layout (shorts): index = (((half*8 + ks)*4 + ct)*64 + lane)*8 + j
// fragment element: B[k = ks*16 + (lane>>5)*8 + j][n = ct*32 + (lane&31)]
struct alignas(16) S8 { short s[8]; };

__global__ __launch_bounds__(256) void init_kernel(int* __restrict__ cnt,
                                                   const float* __restrict__ W1,
                                                   const float* __restrict__ W2,
                                                   const float* __restrict__ W3,
                                                   short* __restrict__ wf1,
                                                   short* __restrict__ wf2,
                                                   short* __restrict__ wf3) {
    int i = blockIdx.x * 256 + threadIdx.x;
    if (i < NN + 1) cnt[i] = 0;
    int item = i - (NN + 1);
    if (item < 0 || item >= 3 * 4096) return;
    int which = item >> 12;
    const float* W = (which == 0) ? W1 : (which == 1) ? W2 : W3;
    short* Wf      = (which == 0) ? wf1 : (which == 1) ? wf2 : wf3;
    int it   = item & 4095;
    int l    = it & 63;
    int ct   = (it >> 6) & 3;
    int ks   = (it >> 8) & 7;
    int half = it >> 11;
    int kbase = ks * 16 + (l >> 5) * 8;
    int n = ct * 32 + (l & 31);
    S8 out;
#pragma unroll
    for (int j = 0; j < 8; j++) {
        float w = W[(kbase + j) * D + n];
        short hi = bf16_rne(w);
        if (half == 0) {
            out.s[j] = hi;
        } else {
            float hif = __uint_as_float(((unsigned)(unsigned short)hi) << 16);
            out.s[j] = (short)(__float_as_uint(w - hif) >> 16);
        }
    }
    ((S8*)Wf)[it] = out;
}

__global__ void count_kernel(const int* __restrict__ dst, int* __restrict__ cnt, int E) {
    int e = blockIdx.x * blockDim.x + threadIdx.x;
    if (e < E) atomicAdd(&cnt[dst[e]], 1);
}

// scan1 + dinv fused
__global__ __launch_bounds__(SCAN_BS) void scan1_kernel(const int* __restrict__ cnt,
                                                        int* __restrict__ rs,
                                                        int* __restrict__ bsum,
                                                        float* __restrict__ dinv, int n) {
    __shared__ int sm[SCAN_BS];
    int i = blockIdx.x * SCAN_BS + threadIdx.x;
    int v = (i < n - 1) ? cnt[i] : 0;
    if (i < n - 1) dinv[i] = rsqrtf((float)v + 1.0f);  // +1 self-loop
    sm[threadIdx.x] = v;
    __syncthreads();
#pragma unroll
    for (int off = 1; off < SCAN_BS; off <<= 1) {
        int t = 0;
        if ((int)threadIdx.x >= off) t = sm[threadIdx.x - off];
        __syncthreads();
        if ((int)threadIdx.x >= off) sm[threadIdx.x] += t;
        __syncthreads();
    }
    int incl = sm[threadIdx.x];
    if (i < n) rs[i] = incl - v;
    if (threadIdx.x == SCAN_BS - 1) bsum[blockIdx.x] = incl;
}

// scan3 with scan2 inlined: every block redundantly scans bsum[0..g) in LDS
__global__ __launch_bounds__(SCAN_BS) void scan3_kernel(int* __restrict__ rs,
                                                        const int* __restrict__ bsum,
                                                        int* __restrict__ cursor,
                                                        int n, int g) {
    __shared__ int sm[128];
    int t = threadIdx.x;
    if (t < 128) sm[t] = (t < g) ? bsum[t] : 0;
    __syncthreads();
#pragma unroll
    for (int off = 1; off < 128; off <<= 1) {
        int tv = 0;
        if (t >= off && t < 128) tv = sm[t - off];
        __syncthreads();
        if (t >= off && t < 128) sm[t] += tv;
        __syncthreads();
    }
    // exclusive offset for this block = inclusive - own value
    int own = ((int)blockIdx.x < g) ? bsum[blockIdx.x] : 0;
    int add = sm[blockIdx.x] - own;
    int i = blockIdx.x * SCAN_BS + t;
    if (i < n) {
        int val = rs[i] + add;
        rs[i] = val;
        if (i < n - 1) cursor[i] = val;
    }
}

// scatter packs {src, bits(dinv[src])}
__global__ void scatter_kernel(const int* __restrict__ srcA, const int* __restrict__ dstA,
                               const float* __restrict__ dinv, int* __restrict__ cursor,
                               int2* __restrict__ csr2, int E) {
    int e = blockIdx.x * blockDim.x + threadIdx.x;
    if (e < E) {
        int d = dstA[e];
        int s = srcA[e];
        int pos = atomicAdd(&cursor[d], 1);
        csr2[pos] = make_int2(s, __float_as_int(dinv[s]));
    }
}

// ---------------- MFMA GEMM: H[M,128](fp16) = X[M,128] @ W[128,128] ----------------
// split-bf16: X@W ~= Xhi@Whi + Xhi@Wlo + Xlo@Whi. X is f32 (layer 1) or fp16 (2,3).
// W fragments read straight from global (L2-hot, wave-uniform) — no LDS, no barrier.
__global__ __launch_bounds__(256) void gemm_mfma(const void* __restrict__ Xv, int x_is_f32,
                                                 const short* __restrict__ Wf,
                                                 h16* __restrict__ H, int M) {
    const int wave = threadIdx.x >> 6;
    const int lane = threadIdx.x & 63;
    const int row0 = blockIdx.x * 128 + wave * 32;
    const int arow = min(row0 + (lane & 31), M - 1);
    const int koff = (lane >> 5) * 8;

    f32x16 acc[4] = {};

#pragma unroll
    for (int ks = 0; ks < 8; ks++) {
        float f[8];
        if (x_is_f32) {
            const float* p = (const float*)Xv + (size_t)arow * D + koff + ks * 16;
            float4 fa = *(const float4*)p;
            float4 fb = *(const float4*)(p + 4);
            f[0] = fa.x; f[1] = fa.y; f[2] = fa.z; f[3] = fa.w;
            f[4] = fb.x; f[5] = fb.y; f[6] = fb.z; f[7] = fb.w;
        } else {
            const h16* p = (const h16*)Xv + (size_t)arow * D + koff + ks * 16;
            h16x8 hv = *(const h16x8*)p;
#pragma unroll
            for (int j = 0; j < 8; j++) f[j] = (float)hv[j];
        }
        bf16x8 ahi, alo;
#pragma unroll
        for (int j = 0; j < 8; j++) {
            unsigned u = __float_as_uint(f[j]);
            ahi[j] = (short)(u >> 16);
            float l = f[j] - __uint_as_float(u & 0xFFFF0000u);
            alo[j] = (short)(__float_as_uint(l) >> 16);
        }
#pragma unroll
        for (int ct = 0; ct < 4; ct++) {
            bf16x8 bhi = *(const bf16x8*)(Wf + (size_t)(((ks * 4 + ct) * 64) + lane) * 8);
            bf16x8 blo = *(const bf16x8*)(Wf + (size_t)(((ks * 4 + ct + 32) * 64) + lane) * 8);
            acc[ct] = __builtin_amdgcn_mfma_f32_32x32x16_bf16(ahi, bhi, acc[ct], 0, 0, 0);
            acc[ct] = __builtin_amdgcn_mfma_f32_32x32x16_bf16(ahi, blo, acc[ct], 0, 0, 0);
            acc[ct] = __builtin_amdgcn_mfma_f32_32x32x16_bf16(alo, bhi, acc[ct], 0, 0, 0);
        }
    }

    // C/D layout (m74/m101): col=lane&31, row=(r&3)+8*(r>>2)+4*(lane>>5)
    const int col0 = lane & 31;
    const int rbase = row0 + 4 * (lane >> 5);
#pragma unroll
    for (int ct = 0; ct < 4; ct++) {
#pragma unroll
        for (int r = 0; r < 16; r++) {
            int row = rbase + (r & 3) + 8 * (r >> 2);
            if (row < M) H[(size_t)row * D + ct * 32 + col0] = (h16)acc[ct][r];
        }
    }
}

// ---------------- aggregation v2 ----------------
// half-wave per edge: lanes 0-31 even edges, 32-63 odd edges; lane covers 4 feats (h16x4).
// combine halves with shfl_xor(32). mode 0: relu + fp16 out; mode 1: f32 out + zero row0.
__global__ __launch_bounds__(256) void agg_kernel(const h16* __restrict__ H,
                                                  const float* __restrict__ dinv,
                                                  const int* __restrict__ rowstart,
                                                  const int2* __restrict__ csr2,
                                                  const float* __restrict__ bias,
                                                  h16* __restrict__ out16,
                                                  float* __restrict__ out32,
                                                  int n, int mode) {
    int node = blockIdx.x * 4 + (threadIdx.x >> 6);
    if (node >= n) return;
    int lane = threadIdx.x & 63;
    int half = lane >> 5;
    int col = (lane & 31) * 4;

    float di = dinv[node];
    float a0 = 0.f, a1 = 0.f, a2 = 0.f, a3 = 0.f;
    float c0 = 0.f, c1 = 0.f, c2 = 0.f, c3 = 0.f;
    if (half) {  // self term on half 1 (half 0 gets the extra edge when count is odd)
        h16x4 hs = *(const h16x4*)(H + (size_t)node * D + col);
        a0 = di * (float)hs[0]; a1 = di * (float)hs[1];
        a2 = di * (float)hs[2]; a3 = di * (float)hs[3];
    }

    int s = rowstart[node];
    int e = rowstart[node + 1];
    int p = s + half;
    while (p + 6 < e) {
        int2 w0 = csr2[p];
        int2 w1 = csr2[p + 2];
        int2 w2 = csr2[p + 4];
        int2 w3 = csr2[p + 6];
        h16x4 v0 = *(const h16x4*)(H + (size_t)w0.x * D + col);
        h16x4 v1 = *(const h16x4*)(H + (size_t)w1.x * D + col);
        h16x4 v2 = *(const h16x4*)(H + (size_t)w2.x * D + col);
        h16x4 v3 = *(const h16x4*)(H + (size_t)w3.x * D + col);
        float f0 = __int_as_float(w0.y), f1 = __int_as_float(w1.y);
        float f2 = __int_as_float(w2.y), f3 = __int_as_float(w3.y);
        a0 = fmaf(f0, (float)v0[0], a0); a1 = fmaf(f0, (float)v0[1], a1);
        a2 = fmaf(f0, (float)v0[2], a2); a3 = fmaf(f0, (float)v0[3], a3);
        c0 = fmaf(f1, (float)v1[0], c0); c1 = fmaf(f1, (float)v1[1], c1);
        c2 = fmaf(f1, (float)v1[2], c2); c3 = fmaf(f1, (float)v1[3], c3);
        a0 = fmaf(f2, (float)v2[0], a0); a1 = fmaf(f2, (float)v2[1], a1);
        a2 = fmaf(f2, (float)v2[2], a2); a3 = fmaf(f2, (float)v2[3], a3);
        c0 = fmaf(f3, (float)v3[0], c0); c1 = fmaf(f3, (float)v3[1], c1);
        c2 = fmaf(f3, (float)v3[2], c2); c3 = fmaf(f3, (float)v3[3], c3);
        p += 8;
    }
    while (p < e) {
        int2 w = csr2[p];
        float f = __int_as_float(w.y);
        h16x4 v = *(const h16x4*)(H + (size_t)w.x * D + col);
        a0 = fmaf(f, (float)v[0], a0); a1 = fmaf(f, (float)v[1], a1);
        a2 = fmaf(f, (float)v[2], a2); a3 = fmaf(f, (float)v[3], a3);
        p += 2;
    }
    a0 += c0; a1 += c1; a2 += c2; a3 += c3;

    // cross-half combine
    a0 += __shfl_xor(a0, 32, 64);
    a1 += __shfl_xor(a1, 32, 64);
    a2 += __shfl_xor(a2, 32, 64);
    a3 += __shfl_xor(a3, 32, 64);

    if (half == 0) {
        float4 bb = *(const float4*)(bias + col);
        float r0 = fmaf(di, a0, bb.x);
        float r1 = fmaf(di, a1, bb.y);
        float r2 = fmaf(di, a2, bb.z);
        float r3 = fmaf(di, a3, bb.w);
        if (mode == 0) {
            r0 = fmaxf(r0, 0.f); r1 = fmaxf(r1, 0.f);
            r2 = fmaxf(r2, 0.f); r3 = fmaxf(r3, 0.f);
            h16x4 o; o[0] = (h16)r0; o[1] = (h16)r1; o[2] = (h16)r2; o[3] = (h16)r3;
            *(h16x4*)(out16 + (size_t)node * D + col) = o;
        } else {
            if (node == 0) { r0 = r1 = r2 = r3 = 0.f; }
            *(float4*)(out32 + (size_t)node * D + col) = make_float4(r0, r1, r2, r3);
        }
    }
}

// ---------------- launch ----------------

extern "C" void kernel_launch(void* const* d_in, const int* in_sizes, int n_in,
                              void* d_out, int out_size, void* d_ws, size_t ws_size,
                              hipStream_t stream) {
    const float* emb = (const float*)d_in[0];
    const float* W1  = (const float*)d_in[1];
    const float* b1  = (const float*)d_in[2];
    const float* W2  = (const float*)d_in[3];
    const float* b2  = (const float*)d_in[4];
    const float* W3  = (const float*)d_in[5];
    const float* b3  = (const float*)d_in[6];
    const int*   ei  = (const int*)d_in[7];

    const int E = in_sizes[7] / 2;
    const int* srcA = ei;
    const int* dstA = ei + E;
    float* out = (float*)d_out;

    char* ws = (char*)d_ws;
    size_t off = 0;
    auto alloc = [&](size_t bytes) -> void* {
        void* p = ws + off;
        off = (off + bytes + 255) & ~(size_t)255;
        return p;
    };
    h16* h      = (h16*)alloc((size_t)NN * D * 2);
    h16* x16    = (h16*)alloc((size_t)NN * D * 2);
    float* dinv = (float*)alloc((size_t)NN * 4);
    int* cnt      = (int*)alloc((size_t)(NN + 1) * 4);
    int* rowstart = (int*)alloc((size_t)(NN + 1) * 4);
    int* cursor   = (int*)alloc((size_t)NN * 4);
    int2* csr2    = (int2*)alloc((size_t)E * 8);
    short* wf1    = (short*)alloc(4096 * 16);
    short* wf2    = (short*)alloc(4096 * 16);
    short* wf3    = (short*)alloc(4096 * 16);
    int* bsum     = (int*)alloc(256 * 4);

    const int T = 256;
    const int n_scan = NN + 1;
    const int scan_grid = (n_scan + SCAN_BS - 1) / SCAN_BS;
    const int init_items = (NN + 1) + 3 * 4096;

    // preprocessing (5 launches)
    init_kernel<<<(init_items + T - 1) / T, T, 0, stream>>>(cnt, W1, W2, W3, wf1, wf2, wf3);
    count_kernel<<<(E + T - 1) / T, T, 0, stream>>>(dstA, cnt, E);
    scan1_kernel<<<scan_grid, SCAN_BS, 0, stream>>>(cnt, rowstart, bsum, dinv, n_scan);
    scan3_kernel<<<scan_grid, SCAN_BS, 0, stream>>>(rowstart, bsum, cursor, n_scan, scan_grid);
    scatter_kernel<<<(E + T - 1) / T, T, 0, stream>>>(srcA, dstA, dinv, cursor, csr2, E);

    const int gemm_grid = (NN + 127) / 128;
    const int agg_grid  = (NN + 3) / 4;

    // layer 1
    gemm_mfma<<<gemm_grid, T, 0, stream>>>(emb, 1, wf1, h, NN);
    agg_kernel<<<agg_grid, T, 0, stream>>>(h, dinv, rowstart, csr2, b1, x16, nullptr, NN, 0);
    // layer 2
    gemm_mfma<<<gemm_grid, T, 0, stream>>>(x16, 0, wf2, h, NN);
    agg_kernel<<<agg_grid, T, 0, stream>>>(h, dinv, rowstart, csr2, b2, x16, nullptr, NN, 0);
    // layer 3
    gemm_mfma<<<gemm_grid, T, 0, stream>>>(x16, 0, wf3, h, NN);
    agg_kernel<<<agg_grid, T, 0, stream>>>(h, dinv, rowstart, csr2, b3, nullptr, out, NN, 1);
}

// Round 6
// 299.899 us; speedup vs baseline: 1.0112x; 1.0112x over previous
//
#include <hip/hip_runtime.h>
#include <hip/hip_fp16.h>

#define NN 50000
#define D 128
#define SCAN_BS 512

typedef __attribute__((ext_vector_type(8))) short bf16x8;
typedef __attribute__((ext_vector_type(16))) float f32x16;
typedef _Float16 h16;
typedef __attribute__((ext_vector_type(4))) _Float16 h16x4;
typedef __attribute__((ext_vector_type(8))) _Float16 h16x8;

struct alignas(16) S8 { short s[8]; };

static __device__ __forceinline__ short bf16_rne(float f) {
    unsigned u = __float_as_uint(f);
    unsigned r = (u + 0x7FFFu + ((u >> 16) & 1u)) >> 16;
    return (short)r;
}

// ---------------- preprocessing ----------------

__global__ void count_kernel(const int* __restrict__ dst, int* __restrict__ cnt, int E) {
    int e = blockIdx.x * blockDim.x + threadIdx.x;
    if (e < E) atomicAdd(&cnt[dst[e]], 1);
}

// scan1 + dinv fused
__global__ __launch_bounds__(SCAN_BS) void scan1_kernel(const int* __restrict__ cnt,
                                                        int* __restrict__ rs,
                                                        int* __restrict__ bsum,
                                                        float* __restrict__ dinv, int n) {
    __shared__ int sm[SCAN_BS];
    int i = blockIdx.x * SCAN_BS + threadIdx.x;
    int v = (i < n - 1) ? cnt[i] : 0;
    if (i < n - 1) dinv[i] = rsqrtf((float)v + 1.0f);  // +1 self-loop
    sm[threadIdx.x] = v;
    __syncthreads();
#pragma unroll
    for (int off = 1; off < SCAN_BS; off <<= 1) {
        int t = 0;
        if ((int)threadIdx.x >= off) t = sm[threadIdx.x - off];
        __syncthreads();
        if ((int)threadIdx.x >= off) sm[threadIdx.x] += t;
        __syncthreads();
    }
    int incl = sm[threadIdx.x];
    if (i < n) rs[i] = incl - v;
    if (threadIdx.x == SCAN_BS - 1) bsum[blockIdx.x] = incl;
}

// scan3 with scan2 inlined: every block redundantly scans bsum[0..g) in LDS
__global__ __launch_bounds__(SCAN_BS) void scan3_kernel(int* __restrict__ rs,
                                                        const int* __restrict__ bsum,
                                                        int* __restrict__ cursor,
                                                        int n, int g) {
    __shared__ int sm[128];
    int t = threadIdx.x;
    if (t < 128) sm[t] = (t < g) ? bsum[t] : 0;
    __syncthreads();
#pragma unroll
    for (int off = 1; off < 128; off <<= 1) {
        int tv = 0;
        if (t >= off && t < 128) tv = sm[t - off];
        __syncthreads();
        if (t >= off && t < 128) sm[t] += tv;
        __syncthreads();
    }
    int own = ((int)blockIdx.x < g) ? bsum[blockIdx.x] : 0;
    int add = sm[blockIdx.x] - own;
    int i = blockIdx.x * SCAN_BS + t;
    if (i < n) {
        int val = rs[i] + add;
        rs[i] = val;
        if (i < n - 1) cursor[i] = val;
    }
}

// scatter packs {src, bits(dinv[src])}
__global__ void scatter_kernel(const int* __restrict__ srcA, const int* __restrict__ dstA,
                               const float* __restrict__ dinv, int* __restrict__ cursor,
                               int2* __restrict__ csr2, int E) {
    int e = blockIdx.x * blockDim.x + threadIdx.x;
    if (e < E) {
        int d = dstA[e];
        int s = srcA[e];
        int pos = atomicAdd(&cursor[d], 1);
        csr2[pos] = make_int2(s, __float_as_int(dinv[s]));
    }
}

// ---------------- MFMA GEMM: H[M,128](fp16) = X[M,128] @ W[128,128](f32) ----------------
// Each block converts W f32 -> split-bf16 fragment layout in LDS (hi | lo), then
// X@W ~= Xhi@Whi + Xhi@Wlo + Xlo@Whi. X is f32 (layer 1) or fp16 (layers 2,3).
// Optionally zeros cnt[] (layer-1 call) to save a dispatch.
__global__ __launch_bounds__(256, 2) void gemm_mfma(const void* __restrict__ Xv, int x_is_f32,
                                                    const float* __restrict__ W,
                                                    h16* __restrict__ H, int M,
                                                    int* __restrict__ cnt_zero) {
    __shared__ short Ws[32768];   // 64 KB: hi frags [0,16384), lo frags [16384,32768)
    {
        // thread -> (ct, l): threads 0..255 cover all (ct in 0..3, l in 0..63) once
        const int l  = threadIdx.x & 63;
        const int ct = threadIdx.x >> 6;
        const int n  = ct * 32 + (l & 31);
        const int lh = l >> 5;
#pragma unroll
        for (int ks = 0; ks < 8; ks++) {
            const int kbase = ks * 16 + lh * 8;
            S8 hi8, lo8;
#pragma unroll
            for (int j = 0; j < 8; j++) {
                float w = W[(kbase + j) * D + n];       // coalesced across lanes (n consecutive)
                short hi = bf16_rne(w);
                float hif = __uint_as_float(((unsigned)(unsigned short)hi) << 16);
                hi8.s[j] = hi;
                lo8.s[j] = (short)(__float_as_uint(w - hif) >> 16);
            }
            const int base = ((ks * 4 + ct) * 64 + l) * 8;
            *(S8*)(Ws + base)         = hi8;
            *(S8*)(Ws + base + 16384) = lo8;
        }
        if (cnt_zero && blockIdx.x < 196) {
            int i = blockIdx.x * 256 + threadIdx.x;
            if (i < NN + 1) cnt_zero[i] = 0;
        }
    }
    __syncthreads();

    const int wave = threadIdx.x >> 6;
    const int lane = threadIdx.x & 63;
    const int row0 = blockIdx.x * 128 + wave * 32;
    const int arow = min(row0 + (lane & 31), M - 1);
    const int koff = (lane >> 5) * 8;

    f32x16 acc[4] = {};

#pragma unroll
    for (int ks = 0; ks < 8; ks++) {
        float f[8];
        if (x_is_f32) {
            const float* p = (const float*)Xv + (size_t)arow * D + koff + ks * 16;
            float4 fa = *(const float4*)p;
            float4 fb = *(const float4*)(p + 4);
            f[0] = fa.x; f[1] = fa.y; f[2] = fa.z; f[3] = fa.w;
            f[4] = fb.x; f[5] = fb.y; f[6] = fb.z; f[7] = fb.w;
        } else {
            const h16* p = (const h16*)Xv + (size_t)arow * D + koff + ks * 16;
            h16x8 hv = *(const h16x8*)p;
#pragma unroll
            for (int j = 0; j < 8; j++) f[j] = (float)hv[j];
        }
        bf16x8 ahi, alo;
#pragma unroll
        for (int j = 0; j < 8; j++) {
            unsigned u = __float_as_uint(f[j]);
            ahi[j] = (short)(u >> 16);
            float l = f[j] - __uint_as_float(u & 0xFFFF0000u);
            alo[j] = (short)(__float_as_uint(l) >> 16);
        }
#pragma unroll
        for (int ct = 0; ct < 4; ct++) {
            const int base = ((ks * 4 + ct) * 64 + lane) * 8;
            bf16x8 bhi = *(const bf16x8*)(Ws + base);
            bf16x8 blo = *(const bf16x8*)(Ws + base + 16384);
            acc[ct] = __builtin_amdgcn_mfma_f32_32x32x16_bf16(ahi, bhi, acc[ct], 0, 0, 0);
            acc[ct] = __builtin_amdgcn_mfma_f32_32x32x16_bf16(ahi, blo, acc[ct], 0, 0, 0);
            acc[ct] = __builtin_amdgcn_mfma_f32_32x32x16_bf16(alo, bhi, acc[ct], 0, 0, 0);
        }
    }

    // C/D layout (m74/m101): col=lane&31, row=(r&3)+8*(r>>2)+4*(lane>>5)
    const int col0 = lane & 31;
    const int rbase = row0 + 4 * (lane >> 5);
#pragma unroll
    for (int ct = 0; ct < 4; ct++) {
#pragma unroll
        for (int r = 0; r < 16; r++) {
            int row = rbase + (r & 3) + 8 * (r >> 2);
            if (row < M) H[(size_t)row * D + ct * 32 + col0] = (h16)acc[ct][r];
        }
    }
}

// ---------------- aggregation v2 ----------------
// half-wave per edge: lanes 0-31 even edges, 32-63 odd edges; lane covers 4 feats (h16x4).
// combine halves with shfl_xor(32). mode 0: relu + fp16 out; mode 1: f32 out + zero row0.
__global__ __launch_bounds__(256) void agg_kernel(const h16* __restrict__ H,
                                                  const float* __restrict__ dinv,
                                                  const int* __restrict__ rowstart,
                                                  const int2* __restrict__ csr2,
                                                  const float* __restrict__ bias,
                                                  h16* __restrict__ out16,
                                                  float* __restrict__ out32,
                                                  int n, int mode) {
    int node = blockIdx.x * 4 + (threadIdx.x >> 6);
    if (node >= n) return;
    int lane = threadIdx.x & 63;
    int half = lane >> 5;
    int col = (lane & 31) * 4;

    float di = dinv[node];
    float a0 = 0.f, a1 = 0.f, a2 = 0.f, a3 = 0.f;
    float c0 = 0.f, c1 = 0.f, c2 = 0.f, c3 = 0.f;
    if (half) {  // self term on half 1 (half 0 gets the extra edge when count is odd)
        h16x4 hs = *(const h16x4*)(H + (size_t)node * D + col);
        a0 = di * (float)hs[0]; a1 = di * (float)hs[1];
        a2 = di * (float)hs[2]; a3 = di * (float)hs[3];
    }

    int s = rowstart[node];
    int e = rowstart[node + 1];
    int p = s + half;
    while (p + 6 < e) {
        int2 w0 = csr2[p];
        int2 w1 = csr2[p + 2];
        int2 w2 = csr2[p + 4];
        int2 w3 = csr2[p + 6];
        h16x4 v0 = *(const h16x4*)(H + (size_t)w0.x * D + col);
        h16x4 v1 = *(const h16x4*)(H + (size_t)w1.x * D + col);
        h16x4 v2 = *(const h16x4*)(H + (size_t)w2.x * D + col);
        h16x4 v3 = *(const h16x4*)(H + (size_t)w3.x * D + col);
        float f0 = __int_as_float(w0.y), f1 = __int_as_float(w1.y);
        float f2 = __int_as_float(w2.y), f3 = __int_as_float(w3.y);
        a0 = fmaf(f0, (float)v0[0], a0); a1 = fmaf(f0, (float)v0[1], a1);
        a2 = fmaf(f0, (float)v0[2], a2); a3 = fmaf(f0, (float)v0[3], a3);
        c0 = fmaf(f1, (float)v1[0], c0); c1 = fmaf(f1, (float)v1[1], c1);
        c2 = fmaf(f1, (float)v1[2], c2); c3 = fmaf(f1, (float)v1[3], c3);
        a0 = fmaf(f2, (float)v2[0], a0); a1 = fmaf(f2, (float)v2[1], a1);
        a2 = fmaf(f2, (float)v2[2], a2); a3 = fmaf(f2, (float)v2[3], a3);
        c0 = fmaf(f3, (float)v3[0], c0); c1 = fmaf(f3, (float)v3[1], c1);
        c2 = fmaf(f3, (float)v3[2], c2); c3 = fmaf(f3, (float)v3[3], c3);
        p += 8;
    }
    while (p < e) {
        int2 w = csr2[p];
        float f = __int_as_float(w.y);
        h16x4 v = *(const h16x4*)(H + (size_t)w.x * D + col);
        a0 = fmaf(f, (float)v[0], a0); a1 = fmaf(f, (float)v[1], a1);
        a2 = fmaf(f, (float)v[2], a2); a3 = fmaf(f, (float)v[3], a3);
        p += 2;
    }
    a0 += c0; a1 += c1; a2 += c2; a3 += c3;

    a0 += __shfl_xor(a0, 32, 64);
    a1 += __shfl_xor(a1, 32, 64);
    a2 += __shfl_xor(a2, 32, 64);
    a3 += __shfl_xor(a3, 32, 64);

    if (half == 0) {
        float4 bb = *(const float4*)(bias + col);
        float r0 = fmaf(di, a0, bb.x);
        float r1 = fmaf(di, a1, bb.y);
        float r2 = fmaf(di, a2, bb.z);
        float r3 = fmaf(di, a3, bb.w);
        if (mode == 0) {
            r0 = fmaxf(r0, 0.f); r1 = fmaxf(r1, 0.f);
            r2 = fmaxf(r2, 0.f); r3 = fmaxf(r3, 0.f);
            h16x4 o; o[0] = (h16)r0; o[1] = (h16)r1; o[2] = (h16)r2; o[3] = (h16)r3;
            *(h16x4*)(out16 + (size_t)node * D + col) = o;
        } else {
            if (node == 0) { r0 = r1 = r2 = r3 = 0.f; }
            *(float4*)(out32 + (size_t)node * D + col) = make_float4(r0, r1, r2, r3);
        }
    }
}

// ---------------- launch ----------------

extern "C" void kernel_launch(void* const* d_in, const int* in_sizes, int n_in,
                              void* d_out, int out_size, void* d_ws, size_t ws_size,
                              hipStream_t stream) {
    const float* emb = (const float*)d_in[0];
    const float* W1  = (const float*)d_in[1];
    const float* b1  = (const float*)d_in[2];
    const float* W2  = (const float*)d_in[3];
    const float* b2  = (const float*)d_in[4];
    const float* W3  = (const float*)d_in[5];
    const float* b3  = (const float*)d_in[6];
    const int*   ei  = (const int*)d_in[7];

    const int E = in_sizes[7] / 2;
    const int* srcA = ei;
    const int* dstA = ei + E;
    float* out = (float*)d_out;

    char* ws = (char*)d_ws;
    size_t off = 0;
    auto alloc = [&](size_t bytes) -> void* {
        void* p = ws + off;
        off = (off + bytes + 255) & ~(size_t)255;
        return p;
    };
    h16* h      = (h16*)alloc((size_t)NN * D * 2);
    h16* x16    = (h16*)alloc((size_t)NN * D * 2);
    float* dinv = (float*)alloc((size_t)NN * 4);
    int* cnt      = (int*)alloc((size_t)(NN + 1) * 4);
    int* rowstart = (int*)alloc((size_t)(NN + 1) * 4);
    int* cursor   = (int*)alloc((size_t)NN * 4);
    int2* csr2    = (int2*)alloc((size_t)E * 8);
    int* bsum     = (int*)alloc(256 * 4);

    const int T = 256;
    const int n_scan = NN + 1;
    const int scan_grid = (n_scan + SCAN_BS - 1) / SCAN_BS;
    const int gemm_grid = (NN + 127) / 128;
    const int agg_grid  = (NN + 3) / 4;

    // layer-1 GEMM is graph-independent: run it first, folding cnt zeroing in.
    gemm_mfma<<<gemm_grid, T, 0, stream>>>(emb, 1, W1, h, NN, cnt);
    // graph preprocessing
    count_kernel<<<(E + T - 1) / T, T, 0, stream>>>(dstA, cnt, E);
    scan1_kernel<<<scan_grid, SCAN_BS, 0, stream>>>(cnt, rowstart, bsum, dinv, n_scan);
    scan3_kernel<<<scan_grid, SCAN_BS, 0, stream>>>(rowstart, bsum, cursor, n_scan, scan_grid);
    scatter_kernel<<<(E + T - 1) / T, T, 0, stream>>>(srcA, dstA, dinv, cursor, csr2, E);
    // layer 1 agg
    agg_kernel<<<agg_grid, T, 0, stream>>>(h, dinv, rowstart, csr2, b1, x16, nullptr, NN, 0);
    // layer 2
    gemm_mfma<<<gemm_grid, T, 0, stream>>>(x16, 0, W2, h, NN, nullptr);
    agg_kernel<<<agg_grid, T, 0, stream>>>(h, dinv, rowstart, csr2, b2, x16, nullptr, NN, 0);
    // layer 3
    gemm_mfma<<<gemm_grid, T, 0, stream>>>(x16, 0, W3, h, NN, nullptr);
    agg_kernel<<<agg_grid, T, 0, stream>>>(h, dinv, rowstart, csr2, b3, nullptr, out, NN, 1);
}

// Round 7
// 274.203 us; speedup vs baseline: 1.1059x; 1.0937x over previous
//
#include <hip/hip_runtime.h>
#include <hip/hip_fp16.h>

#define NN 50000
#define D 128
#define SCAN_BS 512

typedef __attribute__((ext_vector_type(8))) short bf16x8;
typedef __attribute__((ext_vector_type(16))) float f32x16;
typedef _Float16 h16;
typedef __attribute__((ext_vector_type(2))) _Float16 h16x2;
typedef __attribute__((ext_vector_type(8))) _Float16 h16x8;

struct alignas(16) S8 { short s[8]; };

static __device__ __forceinline__ short bf16_rne(float f) {
    unsigned u = __float_as_uint(f);
    unsigned r = (u + 0x7FFFu + ((u >> 16) & 1u)) >> 16;
    return (short)r;
}

// ---------------- preprocessing ----------------

__global__ void count_kernel(const int* __restrict__ dst, int* __restrict__ cnt, int E) {
    int e = blockIdx.x * blockDim.x + threadIdx.x;
    if (e < E) atomicAdd(&cnt[dst[e]], 1);
}

// scan1 + dinv fused; scans PADDED counts (round up to multiple of 4)
__global__ __launch_bounds__(SCAN_BS) void scan1_kernel(const int* __restrict__ cnt,
                                                        int* __restrict__ rs,
                                                        int* __restrict__ bsum,
                                                        float* __restrict__ dinv, int n) {
    __shared__ int sm[SCAN_BS];
    int i = blockIdx.x * SCAN_BS + threadIdx.x;
    int c = (i < n - 1) ? cnt[i] : 0;
    int v = (c + 3) & ~3;                     // padded count
    if (i < n - 1) dinv[i] = rsqrtf((float)c + 1.0f);  // +1 self-loop
    sm[threadIdx.x] = v;
    __syncthreads();
#pragma unroll
    for (int off = 1; off < SCAN_BS; off <<= 1) {
        int t = 0;
        if ((int)threadIdx.x >= off) t = sm[threadIdx.x - off];
        __syncthreads();
        if ((int)threadIdx.x >= off) sm[threadIdx.x] += t;
        __syncthreads();
    }
    int incl = sm[threadIdx.x];
    if (i < n) rs[i] = incl - v;
    if (threadIdx.x == SCAN_BS - 1) bsum[blockIdx.x] = incl;
}

// scan3 with scan2 inlined + pad-slot fill ({src=0, w=0} — exact no-op edges)
__global__ __launch_bounds__(SCAN_BS) void scan3_kernel(int* __restrict__ rs,
                                                        const int* __restrict__ bsum,
                                                        int* __restrict__ cursor,
                                                        const int* __restrict__ cnt,
                                                        int2* __restrict__ csr2,
                                                        int n, int g) {
    __shared__ int sm[128];
    int t = threadIdx.x;
    if (t < 128) sm[t] = (t < g) ? bsum[t] : 0;
    __syncthreads();
#pragma unroll
    for (int off = 1; off < 128; off <<= 1) {
        int tv = 0;
        if (t >= off && t < 128) tv = sm[t - off];
        __syncthreads();
        if (t >= off && t < 128) sm[t] += tv;
        __syncthreads();
    }
    int own = ((int)blockIdx.x < g) ? bsum[blockIdx.x] : 0;
    int add = sm[blockIdx.x] - own;
    int i = blockIdx.x * SCAN_BS + t;
    if (i < n) {
        int val = rs[i] + add;
        rs[i] = val;
        if (i < n - 1) {
            cursor[i] = val;
            int c = cnt[i];
            int pc = (c + 3) & ~3;
            for (int j = val + c; j < val + pc; j++) csr2[j] = make_int2(0, 0);
        }
    }
}

// scatter packs {src, bits(dinv[src])} into the real-edge prefix of each row
__global__ void scatter_kernel(const int* __restrict__ srcA, const int* __restrict__ dstA,
                               const float* __restrict__ dinv, int* __restrict__ cursor,
                               int2* __restrict__ csr2, int E) {
    int e = blockIdx.x * blockDim.x + threadIdx.x;
    if (e < E) {
        int d = dstA[e];
        int s = srcA[e];
        int pos = atomicAdd(&cursor[d], 1);
        csr2[pos] = make_int2(s, __float_as_int(dinv[s]));
    }
}

// ---------------- MFMA GEMM: H[M,128](fp16) = X[M,128] @ W[128,128](f32) ----------------
// Block converts W f32 -> split-bf16 fragments in LDS (hi|lo), then
// X@W ~= Xhi@Whi + Xhi@Wlo + Xlo@Whi. X is f32 (layer 1) or fp16 (layers 2,3).
__global__ __launch_bounds__(256, 2) void gemm_mfma(const void* __restrict__ Xv, int x_is_f32,
                                                    const float* __restrict__ W,
                                                    h16* __restrict__ H, int M,
                                                    int* __restrict__ cnt_zero) {
    __shared__ short Ws[32768];   // 64 KB: hi frags [0,16384), lo frags [16384,32768)
    {
        const int l  = threadIdx.x & 63;
        const int ct = threadIdx.x >> 6;
        const int n  = ct * 32 + (l & 31);
        const int lh = l >> 5;
#pragma unroll
        for (int ks = 0; ks < 8; ks++) {
            const int kbase = ks * 16 + lh * 8;
            S8 hi8, lo8;
#pragma unroll
            for (int j = 0; j < 8; j++) {
                float w = W[(kbase + j) * D + n];
                short hi = bf16_rne(w);
                float hif = __uint_as_float(((unsigned)(unsigned short)hi) << 16);
                hi8.s[j] = hi;
                lo8.s[j] = (short)(__float_as_uint(w - hif) >> 16);
            }
            const int base = ((ks * 4 + ct) * 64 + l) * 8;
            *(S8*)(Ws + base)         = hi8;
            *(S8*)(Ws + base + 16384) = lo8;
        }
        if (cnt_zero && blockIdx.x < 196) {
            int i = blockIdx.x * 256 + threadIdx.x;
            if (i < NN + 1) cnt_zero[i] = 0;
        }
    }
    __syncthreads();

    const int wave = threadIdx.x >> 6;
    const int lane = threadIdx.x & 63;
    const int row0 = blockIdx.x * 128 + wave * 32;
    const int arow = min(row0 + (lane & 31), M - 1);
    const int koff = (lane >> 5) * 8;

    f32x16 acc[4] = {};

#pragma unroll
    for (int ks = 0; ks < 8; ks++) {
        float f[8];
        if (x_is_f32) {
            const float* p = (const float*)Xv + (size_t)arow * D + koff + ks * 16;
            float4 fa = *(const float4*)p;
            float4 fb = *(const float4*)(p + 4);
            f[0] = fa.x; f[1] = fa.y; f[2] = fa.z; f[3] = fa.w;
            f[4] = fb.x; f[5] = fb.y; f[6] = fb.z; f[7] = fb.w;
        } else {
            const h16* p = (const h16*)Xv + (size_t)arow * D + koff + ks * 16;
            h16x8 hv = *(const h16x8*)p;
#pragma unroll
            for (int j = 0; j < 8; j++) f[j] = (float)hv[j];
        }
        bf16x8 ahi, alo;
#pragma unroll
        for (int j = 0; j < 8; j++) {
            unsigned u = __float_as_uint(f[j]);
            ahi[j] = (short)(u >> 16);
            float l = f[j] - __uint_as_float(u & 0xFFFF0000u);
            alo[j] = (short)(__float_as_uint(l) >> 16);
        }
#pragma unroll
        for (int ct = 0; ct < 4; ct++) {
            const int base = ((ks * 4 + ct) * 64 + lane) * 8;
            bf16x8 bhi = *(const bf16x8*)(Ws + base);
            bf16x8 blo = *(const bf16x8*)(Ws + base + 16384);
            acc[ct] = __builtin_amdgcn_mfma_f32_32x32x16_bf16(ahi, bhi, acc[ct], 0, 0, 0);
            acc[ct] = __builtin_amdgcn_mfma_f32_32x32x16_bf16(ahi, blo, acc[ct], 0, 0, 0);
            acc[ct] = __builtin_amdgcn_mfma_f32_32x32x16_bf16(alo, bhi, acc[ct], 0, 0, 0);
        }
    }

    // C/D layout (m74/m101): col=lane&31, row=(r&3)+8*(r>>2)+4*(lane>>5)
    const int col0 = lane & 31;
    const int rbase = row0 + 4 * (lane >> 5);
#pragma unroll
    for (int ct = 0; ct < 4; ct++) {
#pragma unroll
        for (int r = 0; r < 16; r++) {
            int row = rbase + (r & 3) + 8 * (r >> 2);
            if (row < M) H[(size_t)row * D + ct * 32 + col0] = (h16)acc[ct][r];
        }
    }
}

// ---------------- aggregation v3 ----------------
// wave per node, lane covers 2 cols (h16x2). Edge rows padded to multiples of 4
// with {src=0,w=0} no-ops: exact-quad loop, no tail. rowstart bounds forced
// uniform via readfirstlane -> csr2 quad reads take the scalar-load path.
__global__ __launch_bounds__(256) void agg_kernel(const h16* __restrict__ H,
                                                  const float* __restrict__ dinv,
                                                  const int* __restrict__ rowstart,
                                                  const int2* __restrict__ csr2,
                                                  const float* __restrict__ bias,
                                                  h16* __restrict__ out16,
                                                  float* __restrict__ out32,
                                                  int n, int mode) {
    int node = blockIdx.x * 4 + (threadIdx.x >> 6);
    if (node >= n) return;
    int lane = threadIdx.x & 63;
    int col = lane * 2;

    float di = dinv[node];
    h16x2 hs = *(const h16x2*)(H + (size_t)node * D + col);
    float ax = di * (float)hs[0];
    float ay = di * (float)hs[1];
    float bx = 0.f, by = 0.f;

    int s = __builtin_amdgcn_readfirstlane(rowstart[node]);
    int e = __builtin_amdgcn_readfirstlane(rowstart[node + 1]);

    for (int p = s; p < e; p += 4) {
        int2 w0 = csr2[p];
        int2 w1 = csr2[p + 1];
        int2 w2 = csr2[p + 2];
        int2 w3 = csr2[p + 3];
        h16x2 v0 = *(const h16x2*)(H + (size_t)w0.x * D + col);
        h16x2 v1 = *(const h16x2*)(H + (size_t)w1.x * D + col);
        h16x2 v2 = *(const h16x2*)(H + (size_t)w2.x * D + col);
        h16x2 v3 = *(const h16x2*)(H + (size_t)w3.x * D + col);
        float f0 = __int_as_float(w0.y), f1 = __int_as_float(w1.y);
        float f2 = __int_as_float(w2.y), f3 = __int_as_float(w3.y);
        ax = fmaf(f0, (float)v0[0], ax); ay = fmaf(f0, (float)v0[1], ay);
        bx = fmaf(f1, (float)v1[0], bx); by = fmaf(f1, (float)v1[1], by);
        ax = fmaf(f2, (float)v2[0], ax); ay = fmaf(f2, (float)v2[1], ay);
        bx = fmaf(f3, (float)v3[0], bx); by = fmaf(f3, (float)v3[1], by);
    }
    ax += bx; ay += by;

    float2 bb = *(const float2*)(bias + col);
    float rx = fmaf(di, ax, bb.x);
    float ry = fmaf(di, ay, bb.y);
    if (mode == 0) {
        rx = fmaxf(rx, 0.f); ry = fmaxf(ry, 0.f);
        h16x2 o; o[0] = (h16)rx; o[1] = (h16)ry;
        *(h16x2*)(out16 + (size_t)node * D + col) = o;
    } else {
        if (node == 0) { rx = 0.f; ry = 0.f; }
        *(float2*)(out32 + (size_t)node * D + col) = make_float2(rx, ry);
    }
}

// ---------------- launch ----------------

extern "C" void kernel_launch(void* const* d_in, const int* in_sizes, int n_in,
                              void* d_out, int out_size, void* d_ws, size_t ws_size,
                              hipStream_t stream) {
    const float* emb = (const float*)d_in[0];
    const float* W1  = (const float*)d_in[1];
    const float* b1  = (const float*)d_in[2];
    const float* W2  = (const float*)d_in[3];
    const float* b2  = (const float*)d_in[4];
    const float* W3  = (const float*)d_in[5];
    const float* b3  = (const float*)d_in[6];
    const int*   ei  = (const int*)d_in[7];

    const int E = in_sizes[7] / 2;
    const int* srcA = ei;
    const int* dstA = ei + E;
    float* out = (float*)d_out;

    char* ws = (char*)d_ws;
    size_t off = 0;
    auto alloc = [&](size_t bytes) -> void* {
        void* p = ws + off;
        off = (off + bytes + 255) & ~(size_t)255;
        return p;
    };
    h16* h      = (h16*)alloc((size_t)NN * D * 2);
    h16* x16    = (h16*)alloc((size_t)NN * D * 2);
    float* dinv = (float*)alloc((size_t)NN * 4);
    int* cnt      = (int*)alloc((size_t)(NN + 1) * 4);
    int* rowstart = (int*)alloc((size_t)(NN + 1) * 4);
    int* cursor   = (int*)alloc((size_t)NN * 4);
    int2* csr2    = (int2*)alloc(((size_t)E + 3 * NN + 64) * 8);  // padded CSR
    int* bsum     = (int*)alloc(256 * 4);

    const int T = 256;
    const int n_scan = NN + 1;
    const int scan_grid = (n_scan + SCAN_BS - 1) / SCAN_BS;
    const int gemm_grid = (NN + 127) / 128;
    const int agg_grid  = (NN + 3) / 4;

    // layer-1 GEMM is graph-independent: run it first, folding cnt zeroing in.
    gemm_mfma<<<gemm_grid, T, 0, stream>>>(emb, 1, W1, h, NN, cnt);
    // graph preprocessing
    count_kernel<<<(E + T - 1) / T, T, 0, stream>>>(dstA, cnt, E);
    scan1_kernel<<<scan_grid, SCAN_BS, 0, stream>>>(cnt, rowstart, bsum, dinv, n_scan);
    scan3_kernel<<<scan_grid, SCAN_BS, 0, stream>>>(rowstart, bsum, cursor, cnt, csr2,
                                                    n_scan, scan_grid);
    scatter_kernel<<<(E + T - 1) / T, T, 0, stream>>>(srcA, dstA, dinv, cursor, csr2, E);
    // layer 1 agg
    agg_kernel<<<agg_grid, T, 0, stream>>>(h, dinv, rowstart, csr2, b1, x16, nullptr, NN, 0);
    // layer 2
    gemm_mfma<<<gemm_grid, T, 0, stream>>>(x16, 0, W2, h, NN, nullptr);
    agg_kernel<<<agg_grid, T, 0, stream>>>(h, dinv, rowstart, csr2, b2, x16, nullptr, NN, 0);
    // layer 3
    gemm_mfma<<<gemm_grid, T, 0, stream>>>(x16, 0, W3, h, NN, nullptr);
    agg_kernel<<<agg_grid, T, 0, stream>>>(h, dinv, rowstart, csr2, b3, nullptr, out, NN, 1);
}